// Round 2
// baseline (390.847 us; speedup 1.0000x reference)
//
#include <hip/hip_runtime.h>
#include <hip/hip_bf16.h>

// LogicConv3d: B=64, C=32, H=32, W=32, K=64, P=28*28=784, S=16 gathers per side.
// Tree: 16 -> 8 -> 4 -> 2 -> 1 soft binary ops with softmax(w)·COEF coefficients.
//
// Two kernels:
//  1) pack_offsets: a_idx/b_idx (19.2 MB of int32 triples) -> packed u16 flat
//     offsets in d_ws (3.2 MB). Offsets fit u16: c*1024+h*32+w <= 32767.
//  2) logicconv_main: block = (k, p-tile, b-chunk). b-chunk pinned to XCD via
//     blockIdx%8 so the 1 MB chunk of x stays in that XCD's 4 MiB L2.
//     __launch_bounds__(256,4) keeps VGPR<=128 -> 4 waves/SIMD.

#define B_  64
#define C_  32
#define H_  32
#define W_  32
#define K_  64
#define P_  784
#define CHW (C_*H_*W_)      // 32768
#define HW  (H_*W_)         // 1024
#define SITES (K_*P_)       // 50176
#define BCHUNK 8

__constant__ float COEF_[16][4] = {
    {0, 0, 0, 0}, {0, 0, 0, 1}, {0, 1, 0, -1}, {0, 1, 0, 0},
    {0, 0, 1, -1}, {0, 0, 1, 0}, {0, 1, 1, -2}, {0, 1, 1, -1},
    {1, -1, -1, 1}, {1, -1, -1, 2}, {1, 0, -1, 0}, {1, 0, -1, 1},
    {1, -1, 0, 0}, {1, -1, 0, 1}, {1, 0, 0, -1}, {1, 0, 0, 0}
};

// ---- kernel 1: pack indices into u16 flat offsets (2 per u32) ----
__global__ __launch_bounds__(256) void pack_offsets(
    const int* __restrict__ a_idx, const int* __restrict__ b_idx,
    uint4* __restrict__ offs)   // [SITES][4] uint4 = 16 u32 = 32 u16 offsets
{
    const int site = blockIdx.x * 256 + threadIdx.x;
    if (site >= SITES) return;

    unsigned int pk[16];
    {
        int tmp[48];
        const int4* v = (const int4*)(a_idx + (size_t)site * 48);
        #pragma unroll
        for (int j = 0; j < 12; ++j) ((int4*)tmp)[j] = v[j];
        #pragma unroll
        for (int l = 0; l < 8; ++l) {
            unsigned int o0 = (unsigned)(tmp[(2*l  )*3+2]*HW + tmp[(2*l  )*3+0]*W_ + tmp[(2*l  )*3+1]);
            unsigned int o1 = (unsigned)(tmp[(2*l+1)*3+2]*HW + tmp[(2*l+1)*3+0]*W_ + tmp[(2*l+1)*3+1]);
            pk[l] = o0 | (o1 << 16);
        }
    }
    {
        int tmp[48];
        const int4* v = (const int4*)(b_idx + (size_t)site * 48);
        #pragma unroll
        for (int j = 0; j < 12; ++j) ((int4*)tmp)[j] = v[j];
        #pragma unroll
        for (int l = 0; l < 8; ++l) {
            unsigned int o0 = (unsigned)(tmp[(2*l  )*3+2]*HW + tmp[(2*l  )*3+0]*W_ + tmp[(2*l  )*3+1]);
            unsigned int o1 = (unsigned)(tmp[(2*l+1)*3+2]*HW + tmp[(2*l+1)*3+0]*W_ + tmp[(2*l+1)*3+1]);
            pk[8 + l] = o0 | (o1 << 16);
        }
    }
    uint4* dst = offs + (size_t)site * 4;
    dst[0] = make_uint4(pk[0],  pk[1],  pk[2],  pk[3]);
    dst[1] = make_uint4(pk[4],  pk[5],  pk[6],  pk[7]);
    dst[2] = make_uint4(pk[8],  pk[9],  pk[10], pk[11]);
    dst[3] = make_uint4(pk[12], pk[13], pk[14], pk[15]);
}

// ---- kernel 2: main ----
__global__ __launch_bounds__(256, 4) void logicconv_main(
    const float* __restrict__ x,
    const float* __restrict__ w0, const float* __restrict__ w1,
    const float* __restrict__ w2, const float* __restrict__ w3,
    const float* __restrict__ w4,
    const uint4* __restrict__ offs,
    float* __restrict__ out)
{
    __shared__ float4 sc[31];   // L0 [0..15], L1 [16..23], L2 [24..27], L3 [28..29], L4 [30]

    const int tid   = threadIdx.x;
    const int bid   = blockIdx.x;
    const int chunk = bid & 7;          // XCD-pinned b-chunk (round-robin dispatch)
    const int t     = bid >> 3;         // 0..255
    const int k     = t >> 2;
    const int ptile = t & 3;

    // ---- coef prologue: 31 threads compute softmax(w)·COEF for this k ----
    if (tid < 31) {
        int d, l;
        if      (tid < 16) { d = 0; l = tid; }
        else if (tid < 24) { d = 1; l = tid - 16; }
        else if (tid < 28) { d = 2; l = tid - 24; }
        else if (tid < 30) { d = 3; l = tid - 28; }
        else               { d = 4; l = 0; }
        const float* W;
        switch (d) {
            case 0: W = w0; break;
            case 1: W = w1; break;
            case 2: W = w2; break;
            case 3: W = w3; break;
            default: W = w4; break;
        }
        const float* row = W + ((size_t)l * K_ + k) * 16;
        float m = row[0];
        #pragma unroll
        for (int o = 1; o < 16; ++o) m = fmaxf(m, row[o]);
        float e[16];
        float Z = 0.0f;
        #pragma unroll
        for (int o = 0; o < 16; ++o) { e[o] = expf(row[o] - m); Z += e[o]; }
        const float inv = 1.0f / Z;
        float c0 = 0.f, c1 = 0.f, c2 = 0.f, c3 = 0.f;
        #pragma unroll
        for (int o = 0; o < 16; ++o) {
            c0 += e[o] * COEF_[o][0];
            c1 += e[o] * COEF_[o][1];
            c2 += e[o] * COEF_[o][2];
            c3 += e[o] * COEF_[o][3];
        }
        sc[tid] = make_float4(c0 * inv, c1 * inv, c2 * inv, c3 * inv);
    }
    __syncthreads();

    const int p = ptile * 256 + tid;
    if (p >= P_) return;   // no further barriers

    const int site = k * P_ + p;
    const uint4 q0 = offs[(size_t)site * 4 + 0];
    const uint4 q1 = offs[(size_t)site * 4 + 1];
    const uint4 q2 = offs[(size_t)site * 4 + 2];
    const uint4 q3 = offs[(size_t)site * 4 + 3];

    int offA[16], offB[16];   // BYTE offsets into one image
    {
        const unsigned int ua[8] = {q0.x, q0.y, q0.z, q0.w, q1.x, q1.y, q1.z, q1.w};
        const unsigned int ub[8] = {q2.x, q2.y, q2.z, q2.w, q3.x, q3.y, q3.z, q3.w};
        #pragma unroll
        for (int j = 0; j < 8; ++j) {
            offA[2*j    ] = (int)((ua[j] & 0xffffu) << 2);
            offA[2*j + 1] = (int)((ua[j] >> 16)     << 2);
            offB[2*j    ] = (int)((ub[j] & 0xffffu) << 2);
            offB[2*j + 1] = (int)((ub[j] >> 16)     << 2);
        }
    }

    const int b0 = chunk * BCHUNK;
    const char* xb = (const char*)(x + (size_t)b0 * CHW);
    for (int i = 0; i < BCHUNK; ++i, xb += (size_t)CHW * 4) {
        float va[16], vb[16];
        #pragma unroll
        for (int l = 0; l < 16; ++l) {
            va[l] = *(const float*)(xb + offA[l]);
            vb[l] = *(const float*)(xb + offB[l]);
        }
        float y[16];
        #pragma unroll
        for (int l = 0; l < 16; ++l) {
            const float4 c = sc[l];
            y[l] = fmaf(c.w, va[l] * vb[l], fmaf(c.z, vb[l], fmaf(c.y, va[l], c.x)));
        }
        #pragma unroll
        for (int l = 0; l < 8; ++l) {
            const float4 c = sc[16 + l];
            const float a = y[2*l], bb = y[2*l + 1];
            y[l] = fmaf(c.w, a * bb, fmaf(c.z, bb, fmaf(c.y, a, c.x)));
        }
        #pragma unroll
        for (int l = 0; l < 4; ++l) {
            const float4 c = sc[24 + l];
            const float a = y[2*l], bb = y[2*l + 1];
            y[l] = fmaf(c.w, a * bb, fmaf(c.z, bb, fmaf(c.y, a, c.x)));
        }
        #pragma unroll
        for (int l = 0; l < 2; ++l) {
            const float4 c = sc[28 + l];
            const float a = y[2*l], bb = y[2*l + 1];
            y[l] = fmaf(c.w, a * bb, fmaf(c.z, bb, fmaf(c.y, a, c.x)));
        }
        {
            const float4 c = sc[30];
            const float a = y[0], bb = y[1];
            y[0] = fmaf(c.w, a * bb, fmaf(c.z, bb, fmaf(c.y, a, c.x)));
        }
        out[((size_t)(b0 + i) * K_ + k) * P_ + p] = y[0];
    }
}

extern "C" void kernel_launch(void* const* d_in, const int* in_sizes, int n_in,
                              void* d_out, int out_size, void* d_ws, size_t ws_size,
                              hipStream_t stream) {
    const float* x     = (const float*)d_in[0];
    const float* w0    = (const float*)d_in[1];
    const float* w1    = (const float*)d_in[2];
    const float* w2    = (const float*)d_in[3];
    const float* w3    = (const float*)d_in[4];
    const float* w4    = (const float*)d_in[5];
    const int*   a_idx = (const int*)d_in[6];
    const int*   b_idx = (const int*)d_in[7];
    float* out = (float*)d_out;
    uint4* offs = (uint4*)d_ws;   // needs SITES*64 B = 3.2 MB

    pack_offsets<<<(SITES + 255) / 256, 256, 0, stream>>>(a_idx, b_idx, offs);

    const int nblocks = 8 * 64 * 4;   // chunk(8) x k(64) x ptile(4) = 2048
    logicconv_main<<<nblocks, 256, 0, stream>>>(x, w0, w1, w2, w3, w4, offs, out);
}

// Round 3
// 266.142 us; speedup vs baseline: 1.4686x; 1.4686x over previous
//
#include <hip/hip_runtime.h>
#include <hip/hip_bf16.h>

// LogicConv3d: B=64, C=32, H=32, W=32, K=64, P=28*28=784, S=16 gathers per side.
// Tree: 16 -> 8 -> 4 -> 2 -> 1 soft binary ops with softmax(w)·COEF coefficients.
//
// R3 design:
//  - pack_offsets prepass: int32 triples (19.2 MB) -> packed u16 flat offsets
//    (3.2 MB in d_ws). Cuts index traffic + main-kernel prologue VGPRs (R2 win).
//  - main kernel: grid (ptile, k, bchunk) with bchunk SLOWEST so all
//    concurrently-resident blocks gather from the same 1 MB slice of x
//    (R1's locality win; R2's bid%8 "XCD pinning" thrashed L2 -> 892 MB fills).
//  - __launch_bounds__(256,4): VGPR<=64 -> high occupancy to hide gather latency.
//  - nontemporal stores for the streamed output.

#define B_  64
#define C_  32
#define H_  32
#define W_  32
#define K_  64
#define P_  784
#define CHW (C_*H_*W_)      // 32768
#define HW  (H_*W_)         // 1024
#define SITES (K_*P_)       // 50176
#define BCHUNK 8

__constant__ float COEF_[16][4] = {
    {0, 0, 0, 0}, {0, 0, 0, 1}, {0, 1, 0, -1}, {0, 1, 0, 0},
    {0, 0, 1, -1}, {0, 0, 1, 0}, {0, 1, 1, -2}, {0, 1, 1, -1},
    {1, -1, -1, 1}, {1, -1, -1, 2}, {1, 0, -1, 0}, {1, 0, -1, 1},
    {1, -1, 0, 0}, {1, -1, 0, 1}, {1, 0, 0, -1}, {1, 0, 0, 0}
};

// ---- kernel 1: pack indices into u16 flat offsets (2 per u32) ----
__global__ __launch_bounds__(256) void pack_offsets(
    const int* __restrict__ a_idx, const int* __restrict__ b_idx,
    uint4* __restrict__ offs)   // [SITES][4] uint4 = 16 u32 = 32 u16 offsets
{
    const int site = blockIdx.x * 256 + threadIdx.x;
    if (site >= SITES) return;

    unsigned int pk[16];
    {
        int tmp[48];
        const int4* v = (const int4*)(a_idx + (size_t)site * 48);
        #pragma unroll
        for (int j = 0; j < 12; ++j) ((int4*)tmp)[j] = v[j];
        #pragma unroll
        for (int l = 0; l < 8; ++l) {
            unsigned int o0 = (unsigned)(tmp[(2*l  )*3+2]*HW + tmp[(2*l  )*3+0]*W_ + tmp[(2*l  )*3+1]);
            unsigned int o1 = (unsigned)(tmp[(2*l+1)*3+2]*HW + tmp[(2*l+1)*3+0]*W_ + tmp[(2*l+1)*3+1]);
            pk[l] = o0 | (o1 << 16);
        }
    }
    {
        int tmp[48];
        const int4* v = (const int4*)(b_idx + (size_t)site * 48);
        #pragma unroll
        for (int j = 0; j < 12; ++j) ((int4*)tmp)[j] = v[j];
        #pragma unroll
        for (int l = 0; l < 8; ++l) {
            unsigned int o0 = (unsigned)(tmp[(2*l  )*3+2]*HW + tmp[(2*l  )*3+0]*W_ + tmp[(2*l  )*3+1]);
            unsigned int o1 = (unsigned)(tmp[(2*l+1)*3+2]*HW + tmp[(2*l+1)*3+0]*W_ + tmp[(2*l+1)*3+1]);
            pk[8 + l] = o0 | (o1 << 16);
        }
    }
    uint4* dst = offs + (size_t)site * 4;
    dst[0] = make_uint4(pk[0],  pk[1],  pk[2],  pk[3]);
    dst[1] = make_uint4(pk[4],  pk[5],  pk[6],  pk[7]);
    dst[2] = make_uint4(pk[8],  pk[9],  pk[10], pk[11]);
    dst[3] = make_uint4(pk[12], pk[13], pk[14], pk[15]);
}

// ---- kernel 2: main ----
__global__ __launch_bounds__(256, 4) void logicconv_main(
    const float* __restrict__ x,
    const float* __restrict__ w0, const float* __restrict__ w1,
    const float* __restrict__ w2, const float* __restrict__ w3,
    const float* __restrict__ w4,
    const uint4* __restrict__ offs,
    float* __restrict__ out)
{
    __shared__ float4 sc[31];   // L0 [0..15], L1 [16..23], L2 [24..27], L3 [28..29], L4 [30]

    const int tid   = threadIdx.x;
    const int ptile = blockIdx.x;     // 0..3 (fastest — fine, shares k slice)
    const int k     = blockIdx.y;     // 0..63
    const int chunk = blockIdx.z;     // 0..7  SLOWEST: concurrent blocks share
                                      //       the same 1 MB slice of x

    // ---- coef prologue: 31 threads compute softmax(w)·COEF for this k ----
    if (tid < 31) {
        int d, l;
        if      (tid < 16) { d = 0; l = tid; }
        else if (tid < 24) { d = 1; l = tid - 16; }
        else if (tid < 28) { d = 2; l = tid - 24; }
        else if (tid < 30) { d = 3; l = tid - 28; }
        else               { d = 4; l = 0; }
        const float* W;
        switch (d) {
            case 0: W = w0; break;
            case 1: W = w1; break;
            case 2: W = w2; break;
            case 3: W = w3; break;
            default: W = w4; break;
        }
        const float* row = W + ((size_t)l * K_ + k) * 16;
        float m = row[0];
        #pragma unroll
        for (int o = 1; o < 16; ++o) m = fmaxf(m, row[o]);
        float e[16];
        float Z = 0.0f;
        #pragma unroll
        for (int o = 0; o < 16; ++o) { e[o] = expf(row[o] - m); Z += e[o]; }
        const float inv = 1.0f / Z;
        float c0 = 0.f, c1 = 0.f, c2 = 0.f, c3 = 0.f;
        #pragma unroll
        for (int o = 0; o < 16; ++o) {
            c0 += e[o] * COEF_[o][0];
            c1 += e[o] * COEF_[o][1];
            c2 += e[o] * COEF_[o][2];
            c3 += e[o] * COEF_[o][3];
        }
        sc[tid] = make_float4(c0 * inv, c1 * inv, c2 * inv, c3 * inv);
    }
    __syncthreads();

    const int p = ptile * 256 + tid;
    if (p >= P_) return;   // no further barriers

    const int site = k * P_ + p;
    const uint4 q0 = offs[(size_t)site * 4 + 0];
    const uint4 q1 = offs[(size_t)site * 4 + 1];
    const uint4 q2 = offs[(size_t)site * 4 + 2];
    const uint4 q3 = offs[(size_t)site * 4 + 3];

    int offA[16], offB[16];   // BYTE offsets into one image
    {
        const unsigned int ua[8] = {q0.x, q0.y, q0.z, q0.w, q1.x, q1.y, q1.z, q1.w};
        const unsigned int ub[8] = {q2.x, q2.y, q2.z, q2.w, q3.x, q3.y, q3.z, q3.w};
        #pragma unroll
        for (int j = 0; j < 8; ++j) {
            offA[2*j    ] = (int)((ua[j] & 0xffffu) << 2);
            offA[2*j + 1] = (int)((ua[j] >> 16)     << 2);
            offB[2*j    ] = (int)((ub[j] & 0xffffu) << 2);
            offB[2*j + 1] = (int)((ub[j] >> 16)     << 2);
        }
    }

    const int b0 = chunk * BCHUNK;
    const char* xb = (const char*)(x + (size_t)b0 * CHW);
    for (int i = 0; i < BCHUNK; ++i, xb += (size_t)CHW * 4) {
        float va[16], vb[16];
        #pragma unroll
        for (int l = 0; l < 16; ++l) {
            va[l] = *(const float*)(xb + offA[l]);
            vb[l] = *(const float*)(xb + offB[l]);
        }
        float y[16];
        #pragma unroll
        for (int l = 0; l < 16; ++l) {
            const float4 c = sc[l];
            y[l] = fmaf(c.w, va[l] * vb[l], fmaf(c.z, vb[l], fmaf(c.y, va[l], c.x)));
        }
        #pragma unroll
        for (int l = 0; l < 8; ++l) {
            const float4 c = sc[16 + l];
            const float a = y[2*l], bb = y[2*l + 1];
            y[l] = fmaf(c.w, a * bb, fmaf(c.z, bb, fmaf(c.y, a, c.x)));
        }
        #pragma unroll
        for (int l = 0; l < 4; ++l) {
            const float4 c = sc[24 + l];
            const float a = y[2*l], bb = y[2*l + 1];
            y[l] = fmaf(c.w, a * bb, fmaf(c.z, bb, fmaf(c.y, a, c.x)));
        }
        #pragma unroll
        for (int l = 0; l < 2; ++l) {
            const float4 c = sc[28 + l];
            const float a = y[2*l], bb = y[2*l + 1];
            y[l] = fmaf(c.w, a * bb, fmaf(c.z, bb, fmaf(c.y, a, c.x)));
        }
        {
            const float4 c = sc[30];
            const float a = y[0], bb = y[1];
            y[0] = fmaf(c.w, a * bb, fmaf(c.z, bb, fmaf(c.y, a, c.x)));
        }
        __builtin_nontemporal_store(y[0], &out[((size_t)(b0 + i) * K_ + k) * P_ + p]);
    }
}

extern "C" void kernel_launch(void* const* d_in, const int* in_sizes, int n_in,
                              void* d_out, int out_size, void* d_ws, size_t ws_size,
                              hipStream_t stream) {
    const float* x     = (const float*)d_in[0];
    const float* w0    = (const float*)d_in[1];
    const float* w1    = (const float*)d_in[2];
    const float* w2    = (const float*)d_in[3];
    const float* w3    = (const float*)d_in[4];
    const float* w4    = (const float*)d_in[5];
    const int*   a_idx = (const int*)d_in[6];
    const int*   b_idx = (const int*)d_in[7];
    float* out = (float*)d_out;
    uint4* offs = (uint4*)d_ws;   // needs SITES*64 B = 3.2 MB

    pack_offsets<<<(SITES + 255) / 256, 256, 0, stream>>>(a_idx, b_idx, offs);

    dim3 grid(4, K_, B_ / BCHUNK);   // z (b-chunk) slowest
    logicconv_main<<<grid, 256, 0, stream>>>(x, w0, w1, w2, w3, w4, offs, out);
}